// Round 13
// baseline (7997.713 us; speedup 1.0000x reference)
//
#include <hip/hip_runtime.h>
#include <stdint.h>

// Bidirectional LSTM T=4096, B=1, I=H=1024 -> 3 classes.
// R13: R12 structure (R8 + eager vmcnt(0) flush after publish) with the h
//      broadcast halved: (epoch16<<16)|fp16(h) packed in u32. Each thread's
//      two words ride in ONE u64 atomic poll load (was two). Broadcast
//      payload 2MB -> 1MB/step; poll ops halved. All math stays fp32;
//      only the cross-block wire format is fp16 (err ~1e-4 << 4.9e-3 thr).

#define T_SEQ 4096
#define ISZ   1024
#define HID   1024
#define NB_TOT 256
#define NTHR  512
#define PAD   68

typedef unsigned long long u64;
typedef unsigned int u32;

__device__ __forceinline__ float fast_sigmoid(float x) {
    return 1.0f / (1.0f + __expf(-x));
}
__device__ __forceinline__ float fast_tanh(float x) {
    return 1.0f - 2.0f / (__expf(2.0f * x) + 1.0f);
}
__device__ __forceinline__ float h16f(unsigned short u) {
    _Float16 h; __builtin_memcpy(&h, &u, 2); return (float)h;
}
__device__ __forceinline__ unsigned short fh16(float f) {
    _Float16 h = (_Float16)f; unsigned short u; __builtin_memcpy(&u, &h, 2); return u;
}

#define PIN4(v) asm volatile("" : "+v"(v.x), "+v"(v.y), "+v"(v.z), "+v"(v.w))
#define DOT4(a, b) ((a).x*(b).x + (a).y*(b).y + (a).z*(b).z + (a).w*(b).w)

// ---------------- Phase 1: xg[dir][t][g] = dot(x[row(t)], Wih[g]) + bih[g] + bhh[g]
#define GM 64
#define GN 64
#define GK 32

__global__ __launch_bounds__(256)
void xproj_gemm(const float* __restrict__ x,
                const float* __restrict__ Wih_f, const float* __restrict__ bih_f,
                const float* __restrict__ bhh_f,
                const float* __restrict__ Wih_b, const float* __restrict__ bih_b,
                const float* __restrict__ bhh_b,
                float* __restrict__ xg)
{
    const int dir = blockIdx.z;
    const float* Wih = dir ? Wih_b : Wih_f;
    const float* bih = dir ? bih_b : bih_f;
    const float* bhh = dir ? bhh_b : bhh_f;
    const int m0 = blockIdx.y * GM;
    const int n0 = blockIdx.x * GN;
    const int tid = threadIdx.x;
    const int ms = tid >> 2;
    const int kq = tid & 3;
    const int tm = tid >> 4;
    const int tn = tid & 15;

    __shared__ float As[GK][GM + 4];
    __shared__ float Bs[GK][GN + 4];

    float acc[4][4] = {};

    const int mrow = m0 + ms;
    const int xrow = dir ? (T_SEQ - 1 - mrow) : mrow;
    const float* ap = x + (size_t)xrow * ISZ + kq * 8;
    const float* bp = Wih + (size_t)(n0 + ms) * ISZ + kq * 8;

    for (int k0 = 0; k0 < ISZ; k0 += GK) {
        float4 a0 = *(const float4*)(ap + k0);
        float4 a1 = *(const float4*)(ap + k0 + 4);
        float4 b0 = *(const float4*)(bp + k0);
        float4 b1 = *(const float4*)(bp + k0 + 4);
        __syncthreads();
        const int kb = kq * 8;
        As[kb+0][ms]=a0.x; As[kb+1][ms]=a0.y; As[kb+2][ms]=a0.z; As[kb+3][ms]=a0.w;
        As[kb+4][ms]=a1.x; As[kb+5][ms]=a1.y; As[kb+6][ms]=a1.z; As[kb+7][ms]=a1.w;
        Bs[kb+0][ms]=b0.x; Bs[kb+1][ms]=b0.y; Bs[kb+2][ms]=b0.z; Bs[kb+3][ms]=b0.w;
        Bs[kb+4][ms]=b1.x; Bs[kb+5][ms]=b1.y; Bs[kb+6][ms]=b1.z; Bs[kb+7][ms]=b1.w;
        __syncthreads();
        #pragma unroll
        for (int k = 0; k < GK; ++k) {
            float4 av = *(const float4*)&As[k][tm * 4];
            float4 bv = *(const float4*)&Bs[k][tn * 4];
            acc[0][0] += av.x*bv.x; acc[0][1] += av.x*bv.y; acc[0][2] += av.x*bv.z; acc[0][3] += av.x*bv.w;
            acc[1][0] += av.y*bv.x; acc[1][1] += av.y*bv.y; acc[1][2] += av.y*bv.z; acc[1][3] += av.y*bv.w;
            acc[2][0] += av.z*bv.x; acc[2][1] += av.z*bv.y; acc[2][2] += av.z*bv.z; acc[2][3] += av.z*bv.w;
            acc[3][0] += av.w*bv.x; acc[3][1] += av.w*bv.y; acc[3][2] += av.w*bv.z; acc[3][3] += av.w*bv.w;
        }
    }

    const int gc = n0 + tn * 4;
    float4 bb1 = *(const float4*)(bih + gc);
    float4 bb2 = *(const float4*)(bhh + gc);
    float bx = bb1.x + bb2.x, by = bb1.y + bb2.y, bz = bb1.z + bb2.z, bw = bb1.w + bb2.w;
    float* op = xg + ((size_t)dir << 24) + (size_t)(m0 + tm * 4) * 4096 + gc;
    #pragma unroll
    for (int i = 0; i < 4; ++i) {
        float4 v;
        v.x = acc[i][0] + bx; v.y = acc[i][1] + by;
        v.z = acc[i][2] + bz; v.w = acc[i][3] + bw;
        *(float4*)(op + (size_t)i * 4096) = v;
    }
}

// ---------------- Phase 2: persistent recurrence, register-resident Whh
__global__ __attribute__((amdgpu_flat_work_group_size(NTHR, NTHR)))
           __attribute__((amdgpu_waves_per_eu(2, 2)))
void bilstm_rec(const float* __restrict__ xg,
                const float* __restrict__ Whh_f, const float* __restrict__ Whh_b,
                u32* hpack)
{
    const int tid = threadIdx.x;
    const int blk = blockIdx.x;
    const int dir = blk >> 7;
    const int lb  = blk & 127;
    const int u0  = lb * 8;
    const int w   = tid >> 6;      // wave index -> unit u0+w
    const int l   = tid & 63;
    const int q   = l >> 4;        // gate 0..3 (i,f,g,o)
    const int kc  = l & 15;        // k-chunk: owns h[64kc .. 64kc+64) for gate q
    const int unit = u0 + w;
    const int grow = q * HID + unit;

    const float* Whh = dir ? Whh_b : Whh_f;
    const float* xgd = xg + ((size_t)dir << 24);
    u32* hp = hpack + (size_t)dir * 2 * HID;   // [2 buf][1024] u32

    __shared__ __align__(16) float lds_h[2][16 * PAD];

    // ---- one-time: 16 NAMED float4 weight fragments (64 floats, one gate row chunk)
    const float* wp = Whh + (size_t)grow * HID + kc * 64;
    float4 w0 = *(const float4*)(wp + 0),  w1 = *(const float4*)(wp + 4);
    float4 w2 = *(const float4*)(wp + 8),  w3 = *(const float4*)(wp + 12);
    float4 w4 = *(const float4*)(wp + 16), w5 = *(const float4*)(wp + 20);
    float4 w6 = *(const float4*)(wp + 24), w7 = *(const float4*)(wp + 28);
    float4 w8 = *(const float4*)(wp + 32), w9 = *(const float4*)(wp + 36);
    float4 wa = *(const float4*)(wp + 40), wb = *(const float4*)(wp + 44);
    float4 wc = *(const float4*)(wp + 48), wd = *(const float4*)(wp + 52);
    float4 we = *(const float4*)(wp + 56), wf = *(const float4*)(wp + 60);
    PIN4(w0); PIN4(w1); PIN4(w2); PIN4(w3);
    PIN4(w4); PIN4(w5); PIN4(w6); PIN4(w7);
    PIN4(w8); PIN4(w9); PIN4(wa); PIN4(wb);
    PIN4(wc); PIN4(wd); PIN4(we); PIN4(wf);

    // activation constants: tanh(x) = 2*sigmoid(2x)-1 -> uniform sigmoid chain
    const float a_scl = (q == 2) ? 2.0f : 1.0f;
    const float a_mul = (q == 2) ? 2.0f : 1.0f;
    const float a_add = (q == 2) ? -1.0f : 0.0f;

    float c_state = 0.0f;          // lane 0 of each wave
    float xgv = 0.0f;              // kc==0 lanes carry gate q's bias+x proj
    if (kc == 0) xgv = xgd[grow];  // t=0 row
    asm volatile("" : "+v"(xgv));

    bool dead = false;

    for (int t = 0; t < T_SEQ; ++t) {
        float s = 0.0f;

        if (t > 0) {
            // ---- poll BOTH words in ONE u64 load: (tag16|h16)(tag16|h16) ----
            const int b = (t - 1) & 1;
            const u64* src = (const u64*)(hp + (size_t)b * HID) + tid;
            const unsigned tg = (unsigned)t & 0xFFFFu;
            u64 e = 0;
            if (!dead) {
                int sp = 0;
                for (;;) {
                    e = __hip_atomic_load(src, __ATOMIC_RELAXED,
                                          __HIP_MEMORY_SCOPE_AGENT);
                    if ((((unsigned)(e >> 16) & 0xFFFFu) == tg) &
                        ((unsigned)(e >> 48) == tg)) break;
                    if (++sp > (1 << 21)) { dead = true; break; }
                    __builtin_amdgcn_s_sleep(1);
                }
            }
            // decode fp16 -> fp32; PAD-68 layout (0 conflicts)
            const int k0 = tid * 2;
            float2 hv;
            hv.x = h16f((unsigned short)(e & 0xFFFFu));
            hv.y = h16f((unsigned short)((e >> 32) & 0xFFFFu));
            *(float2*)&lds_h[b][(k0 >> 6) * PAD + (k0 & 63)] = hv;
            __syncthreads();

            // ---- 16 b128 reads of this lane's 64-float h chunk ----
            const float* lh = &lds_h[b][kc * PAD];
            float4 h0 = *(const float4*)(lh + 0),  h1 = *(const float4*)(lh + 4);
            float4 h2 = *(const float4*)(lh + 8),  h3 = *(const float4*)(lh + 12);
            float4 h4 = *(const float4*)(lh + 16), h5 = *(const float4*)(lh + 20);
            float4 h6 = *(const float4*)(lh + 24), h7 = *(const float4*)(lh + 28);
            s  = DOT4(w0,h0) + DOT4(w1,h1) + DOT4(w2,h2) + DOT4(w3,h3);
            s += DOT4(w4,h4) + DOT4(w5,h5) + DOT4(w6,h6) + DOT4(w7,h7);
            float4 h8 = *(const float4*)(lh + 32), h9 = *(const float4*)(lh + 36);
            float4 ha = *(const float4*)(lh + 40), hb = *(const float4*)(lh + 44);
            float4 hc = *(const float4*)(lh + 48), hd = *(const float4*)(lh + 52);
            float4 he = *(const float4*)(lh + 56), hf = *(const float4*)(lh + 60);
            s += DOT4(w8,h8) + DOT4(w9,h9) + DOT4(wa,ha) + DOT4(wb,hb);
            s += DOT4(wc,hc) + DOT4(wd,hd) + DOT4(we,he) + DOT4(wf,hf);
        }

        // ---- reduce over the 16 kc lanes (4-stage chain) ----
        s += __shfl_xor(s, 1);
        s += __shfl_xor(s, 2);
        s += __shfl_xor(s, 4);
        s += __shfl_xor(s, 8);

        // kc==0 lanes (l = 0,16,32,48) hold gate preacts; activate in parallel
        float pg = s + xgv;
        float act = a_mul * fast_sigmoid(a_scl * pg) + a_add;

        // gather activated gates to lane 0
        float sf = __shfl(act, 16);
        float tg2 = __shfl(act, 32);
        float so = __shfl(act, 48);

        if (l == 0) {
            float si = act;
            c_state = sf * c_state + si * tg2;
            float hval = so * fast_tanh(c_state);
            u32 pk = (((u32)(t + 1) & 0xFFFFu) << 16) | (u32)fh16(hval);
            __hip_atomic_store(hp + (size_t)(t & 1) * HID + unit, pk,
                               __ATOMIC_RELAXED, __HIP_MEMORY_SCOPE_AGENT);
        }
        // eager flush (R12, +3%): push publish store to coherence point now
        asm volatile("s_waitcnt vmcnt(0)" ::: "memory");

        // prefetch next xg row (hides under next poll window)
        if (t + 1 < T_SEQ && kc == 0) {
            xgv = xgd[(size_t)(t + 1) * 4096 + grow];
            asm volatile("" : "+v"(xgv));
        }
    }
}

// ---------------- head
__global__ void head_kernel(const float* __restrict__ W_ho,
                            const float* __restrict__ b_ho,
                            const u32* __restrict__ hpack,
                            float* __restrict__ out)
{
    const u32* hf  = hpack + 1 * HID;            // dir0 buf1
    const u32* hbk = hpack + 3 * HID;            // dir1 buf1
    __shared__ float r0[4], r1[4], r2[4];
    int tid = threadIdx.x;  // 256
    float p0 = 0.f, p1 = 0.f, p2 = 0.f;
    for (int i = tid; i < 2 * HID; i += 256) {
        u32 e = (i < HID) ? hf[i] : hbk[i - HID];
        _Float16 hh; unsigned short us = (unsigned short)(e & 0xFFFFu);
        __builtin_memcpy(&hh, &us, 2);
        float hv = (float)hh;
        p0 += W_ho[0 * 2 * HID + i] * hv;
        p1 += W_ho[1 * 2 * HID + i] * hv;
        p2 += W_ho[2 * 2 * HID + i] * hv;
    }
    #pragma unroll
    for (int m = 1; m < 64; m <<= 1) {
        p0 += __shfl_xor(p0, m);
        p1 += __shfl_xor(p1, m);
        p2 += __shfl_xor(p2, m);
    }
    int w = tid >> 6;
    if ((tid & 63) == 0) { r0[w] = p0; r1[w] = p1; r2[w] = p2; }
    __syncthreads();
    if (tid == 0) {
        out[0] = b_ho[0] + r0[0] + r0[1] + r0[2] + r0[3];
        out[1] = b_ho[1] + r1[0] + r1[1] + r1[2] + r1[3];
        out[2] = b_ho[2] + r2[0] + r2[1] + r2[2] + r2[3];
    }
}

extern "C" void kernel_launch(void* const* d_in, const int* in_sizes, int n_in,
                              void* d_out, int out_size, void* d_ws, size_t ws_size,
                              hipStream_t stream) {
    const float* x     = (const float*)d_in[0];
    const float* Wih_f = (const float*)d_in[1];
    const float* Whh_f = (const float*)d_in[2];
    const float* bih_f = (const float*)d_in[3];
    const float* bhh_f = (const float*)d_in[4];
    const float* Wih_b = (const float*)d_in[5];
    const float* Whh_b = (const float*)d_in[6];
    const float* bih_b = (const float*)d_in[7];
    const float* bhh_b = (const float*)d_in[8];
    const float* W_ho  = (const float*)d_in[9];
    const float* b_ho  = (const float*)d_in[10];

    u32* hpack = (u32*)d_ws;                       // 16 KB packed (tag16|h16)
    float* xg = (float*)((char*)d_ws + 32768);     // 128 MB xg buffer

    // zero tags every call (ws poisoned once, never re-poisoned between replays)
    hipMemsetAsync(d_ws, 0, 2 * 2 * HID * sizeof(u32), stream);

    dim3 gg(4096 / GN, T_SEQ / GM, 2);
    xproj_gemm<<<gg, 256, 0, stream>>>(x, Wih_f, bih_f, bhh_f,
                                       Wih_b, bih_b, bhh_b, xg);
    bilstm_rec<<<NB_TOT, NTHR, 0, stream>>>(xg, Whh_f, Whh_b, hpack);
    head_kernel<<<1, 256, 0, stream>>>(W_ho, b_ho, hpack, (float*)d_out);
}

// Round 14
// 7394.352 us; speedup vs baseline: 1.0816x; 1.0816x over previous
//
#include <hip/hip_runtime.h>
#include <stdint.h>

// Bidirectional LSTM T=4096, B=1, I=H=1024 -> 3 classes.
// R14: rec kernel byte-identical to R13 (best: 7.31ms, R12 eager-flush + fp16
//      h wire). ONE additive change: the input-projection GEMM now runs on
//      f16 MFMA (16x16x32) with fp32 accum -- fp32 VALU gemm was ~105TF,
//      already near the 157TF vector ceiling; matrix cores were idle.
//      x/Wih converted to fp16 in ws (fallback to fp32 gemm if ws too small).

#define T_SEQ 4096
#define ISZ   1024
#define HID   1024
#define NB_TOT 256
#define NTHR  512
#define PAD   68

typedef unsigned long long u64;
typedef unsigned int u32;
typedef _Float16 half8 __attribute__((ext_vector_type(8)));
typedef float f32x4 __attribute__((ext_vector_type(4)));

__device__ __forceinline__ float fast_sigmoid(float x) {
    return 1.0f / (1.0f + __expf(-x));
}
__device__ __forceinline__ float fast_tanh(float x) {
    return 1.0f - 2.0f / (__expf(2.0f * x) + 1.0f);
}
__device__ __forceinline__ float h16f(unsigned short u) {
    _Float16 h; __builtin_memcpy(&h, &u, 2); return (float)h;
}
__device__ __forceinline__ unsigned short fh16(float f) {
    _Float16 h = (_Float16)f; unsigned short u; __builtin_memcpy(&u, &h, 2); return u;
}

#define PIN4(v) asm volatile("" : "+v"(v.x), "+v"(v.y), "+v"(v.z), "+v"(v.w))
#define DOT4(a, b) ((a).x*(b).x + (a).y*(b).y + (a).z*(b).z + (a).w*(b).w)

// ---------------- fp32 -> fp16 conversion (n multiple of 8)
__global__ __launch_bounds__(256)
void f32_to_f16(const float* __restrict__ src, _Float16* __restrict__ dst, int n)
{
    int i = (blockIdx.x * 256 + threadIdx.x) * 8;
    if (i < n) {
        float4 v0 = *(const float4*)(src + i);
        float4 v1 = *(const float4*)(src + i + 4);
        half8 h;
        h[0] = (_Float16)v0.x; h[1] = (_Float16)v0.y;
        h[2] = (_Float16)v0.z; h[3] = (_Float16)v0.w;
        h[4] = (_Float16)v1.x; h[5] = (_Float16)v1.y;
        h[6] = (_Float16)v1.z; h[7] = (_Float16)v1.w;
        *(half8*)(dst + i) = h;
    }
}

// ---------------- Phase 1 (MFMA): xg[dir][t][g] = x . Wih^T + bih + bhh
__global__ __launch_bounds__(256)
void xproj_mfma(const _Float16* __restrict__ x16,
                const _Float16* __restrict__ w16f, const _Float16* __restrict__ w16b,
                const float* __restrict__ bih_f, const float* __restrict__ bhh_f,
                const float* __restrict__ bih_b, const float* __restrict__ bhh_b,
                float* __restrict__ xg)
{
    const int dir = blockIdx.z;
    const _Float16* W = dir ? w16b : w16f;
    const float* bih = dir ? bih_b : bih_f;
    const float* bhh = dir ? bhh_b : bhh_f;
    const int m0 = blockIdx.y * 64;    // t tile
    const int n0 = blockIdx.x * 64;    // gate-row tile
    const int tid = threadIdx.x;
    const int wid = tid >> 6;          // 4 waves -> 2x2 of 32x32 quadrants
    const int l   = tid & 63;
    const int wm = (wid >> 1) * 32, wn = (wid & 1) * 32;

    __shared__ _Float16 As[64][40];    // +8 pad: spreads banks
    __shared__ _Float16 Bs[64][40];

    f32x4 acc00 = {}, acc01 = {}, acc10 = {}, acc11 = {};

    const int arow = tid >> 2;         // 0..63 staging row
    const int aseg = (tid & 3) * 8;    // k-segment
    const int xrow = dir ? (T_SEQ - 1 - (m0 + arow)) : (m0 + arow);
    const _Float16* ap = x16 + (size_t)xrow * ISZ + aseg;
    const _Float16* bp = W + (size_t)(n0 + arow) * ISZ + aseg;

    const int fr = l & 15, ko = (l >> 4) * 8;

    for (int k0 = 0; k0 < ISZ; k0 += 32) {
        half8 av = *(const half8*)(ap + k0);
        half8 bv = *(const half8*)(bp + k0);
        __syncthreads();               // protect previous iter's frag reads
        *(half8*)&As[arow][aseg] = av;
        *(half8*)&Bs[arow][aseg] = bv;
        __syncthreads();
        // fragments: lane&15 = M/N row, lane>>4 = k-octet (contiguous 8 k)
        half8 a0 = *(const half8*)&As[wm + fr][ko];
        half8 a1 = *(const half8*)&As[wm + 16 + fr][ko];
        half8 b0 = *(const half8*)&Bs[wn + fr][ko];
        half8 b1 = *(const half8*)&Bs[wn + 16 + fr][ko];
        acc00 = __builtin_amdgcn_mfma_f32_16x16x32_f16(a0, b0, acc00, 0, 0, 0);
        acc01 = __builtin_amdgcn_mfma_f32_16x16x32_f16(a0, b1, acc01, 0, 0, 0);
        acc10 = __builtin_amdgcn_mfma_f32_16x16x32_f16(a1, b0, acc10, 0, 0, 0);
        acc11 = __builtin_amdgcn_mfma_f32_16x16x32_f16(a1, b1, acc11, 0, 0, 0);
    }

    // C/D layout (m89-verified): col = lane&15, row = (lane>>4)*4 + r
    const int cc = l & 15, cr = (l >> 4) * 4;
    float* xgd = xg + ((size_t)dir << 24);
    #pragma unroll
    for (int i = 0; i < 2; ++i) {
        #pragma unroll
        for (int j = 0; j < 2; ++j) {
            f32x4 a = (i == 0) ? (j == 0 ? acc00 : acc01)
                               : (j == 0 ? acc10 : acc11);
            int gm = m0 + wm + i * 16 + cr;
            int gn = n0 + wn + j * 16 + cc;
            float bias = bih[gn] + bhh[gn];
            float* op = xgd + (size_t)gm * 4096 + gn;
            op[0]                 = a[0] + bias;
            op[(size_t)1 * 4096]  = a[1] + bias;
            op[(size_t)2 * 4096]  = a[2] + bias;
            op[(size_t)3 * 4096]  = a[3] + bias;
        }
    }
}

// ---------------- Phase 1 fallback (fp32 VALU gemm, used if ws too small)
#define GM 64
#define GN 64
#define GK 32

__global__ __launch_bounds__(256)
void xproj_gemm(const float* __restrict__ x,
                const float* __restrict__ Wih_f, const float* __restrict__ bih_f,
                const float* __restrict__ bhh_f,
                const float* __restrict__ Wih_b, const float* __restrict__ bih_b,
                const float* __restrict__ bhh_b,
                float* __restrict__ xg)
{
    const int dir = blockIdx.z;
    const float* Wih = dir ? Wih_b : Wih_f;
    const float* bih = dir ? bih_b : bih_f;
    const float* bhh = dir ? bhh_b : bhh_f;
    const int m0 = blockIdx.y * GM;
    const int n0 = blockIdx.x * GN;
    const int tid = threadIdx.x;
    const int ms = tid >> 2;
    const int kq = tid & 3;
    const int tm = tid >> 4;
    const int tn = tid & 15;

    __shared__ float As[GK][GM + 4];
    __shared__ float Bs[GK][GN + 4];

    float acc[4][4] = {};

    const int mrow = m0 + ms;
    const int xrow = dir ? (T_SEQ - 1 - mrow) : mrow;
    const float* ap = x + (size_t)xrow * ISZ + kq * 8;
    const float* bp = Wih + (size_t)(n0 + ms) * ISZ + kq * 8;

    for (int k0 = 0; k0 < ISZ; k0 += GK) {
        float4 a0 = *(const float4*)(ap + k0);
        float4 a1 = *(const float4*)(ap + k0 + 4);
        float4 b0 = *(const float4*)(bp + k0);
        float4 b1 = *(const float4*)(bp + k0 + 4);
        __syncthreads();
        const int kb = kq * 8;
        As[kb+0][ms]=a0.x; As[kb+1][ms]=a0.y; As[kb+2][ms]=a0.z; As[kb+3][ms]=a0.w;
        As[kb+4][ms]=a1.x; As[kb+5][ms]=a1.y; As[kb+6][ms]=a1.z; As[kb+7][ms]=a1.w;
        Bs[kb+0][ms]=b0.x; Bs[kb+1][ms]=b0.y; Bs[kb+2][ms]=b0.z; Bs[kb+3][ms]=b0.w;
        Bs[kb+4][ms]=b1.x; Bs[kb+5][ms]=b1.y; Bs[kb+6][ms]=b1.z; Bs[kb+7][ms]=b1.w;
        __syncthreads();
        #pragma unroll
        for (int k = 0; k < GK; ++k) {
            float4 av = *(const float4*)&As[k][tm * 4];
            float4 bv = *(const float4*)&Bs[k][tn * 4];
            acc[0][0] += av.x*bv.x; acc[0][1] += av.x*bv.y; acc[0][2] += av.x*bv.z; acc[0][3] += av.x*bv.w;
            acc[1][0] += av.y*bv.x; acc[1][1] += av.y*bv.y; acc[1][2] += av.y*bv.z; acc[1][3] += av.y*bv.w;
            acc[2][0] += av.z*bv.x; acc[2][1] += av.z*bv.y; acc[2][2] += av.z*bv.z; acc[2][3] += av.z*bv.w;
            acc[3][0] += av.w*bv.x; acc[3][1] += av.w*bv.y; acc[3][2] += av.w*bv.z; acc[3][3] += av.w*bv.w;
        }
    }

    const int gc = n0 + tn * 4;
    float4 bb1 = *(const float4*)(bih + gc);
    float4 bb2 = *(const float4*)(bhh + gc);
    float bx = bb1.x + bb2.x, by = bb1.y + bb2.y, bz = bb1.z + bb2.z, bw = bb1.w + bb2.w;
    float* op = xg + ((size_t)dir << 24) + (size_t)(m0 + tm * 4) * 4096 + gc;
    #pragma unroll
    for (int i = 0; i < 4; ++i) {
        float4 v;
        v.x = acc[i][0] + bx; v.y = acc[i][1] + by;
        v.z = acc[i][2] + bz; v.w = acc[i][3] + bw;
        *(float4*)(op + (size_t)i * 4096) = v;
    }
}

// ---------------- Phase 2: persistent recurrence (byte-identical to R13)
__global__ __attribute__((amdgpu_flat_work_group_size(NTHR, NTHR)))
           __attribute__((amdgpu_waves_per_eu(2, 2)))
void bilstm_rec(const float* __restrict__ xg,
                const float* __restrict__ Whh_f, const float* __restrict__ Whh_b,
                u32* hpack)
{
    const int tid = threadIdx.x;
    const int blk = blockIdx.x;
    const int dir = blk >> 7;
    const int lb  = blk & 127;
    const int u0  = lb * 8;
    const int w   = tid >> 6;      // wave index -> unit u0+w
    const int l   = tid & 63;
    const int q   = l >> 4;        // gate 0..3 (i,f,g,o)
    const int kc  = l & 15;        // k-chunk: owns h[64kc .. 64kc+64) for gate q
    const int unit = u0 + w;
    const int grow = q * HID + unit;

    const float* Whh = dir ? Whh_b : Whh_f;
    const float* xgd = xg + ((size_t)dir << 24);
    u32* hp = hpack + (size_t)dir * 2 * HID;   // [2 buf][1024] u32

    __shared__ __align__(16) float lds_h[2][16 * PAD];

    const float* wp = Whh + (size_t)grow * HID + kc * 64;
    float4 w0 = *(const float4*)(wp + 0),  w1 = *(const float4*)(wp + 4);
    float4 w2 = *(const float4*)(wp + 8),  w3 = *(const float4*)(wp + 12);
    float4 w4 = *(const float4*)(wp + 16), w5 = *(const float4*)(wp + 20);
    float4 w6 = *(const float4*)(wp + 24), w7 = *(const float4*)(wp + 28);
    float4 w8 = *(const float4*)(wp + 32), w9 = *(const float4*)(wp + 36);
    float4 wa = *(const float4*)(wp + 40), wb = *(const float4*)(wp + 44);
    float4 wc = *(const float4*)(wp + 48), wd = *(const float4*)(wp + 52);
    float4 we = *(const float4*)(wp + 56), wf = *(const float4*)(wp + 60);
    PIN4(w0); PIN4(w1); PIN4(w2); PIN4(w3);
    PIN4(w4); PIN4(w5); PIN4(w6); PIN4(w7);
    PIN4(w8); PIN4(w9); PIN4(wa); PIN4(wb);
    PIN4(wc); PIN4(wd); PIN4(we); PIN4(wf);

    const float a_scl = (q == 2) ? 2.0f : 1.0f;
    const float a_mul = (q == 2) ? 2.0f : 1.0f;
    const float a_add = (q == 2) ? -1.0f : 0.0f;

    float c_state = 0.0f;
    float xgv = 0.0f;
    if (kc == 0) xgv = xgd[grow];
    asm volatile("" : "+v"(xgv));

    bool dead = false;

    for (int t = 0; t < T_SEQ; ++t) {
        float s = 0.0f;

        if (t > 0) {
            const int b = (t - 1) & 1;
            const u64* src = (const u64*)(hp + (size_t)b * HID) + tid;
            const unsigned tg = (unsigned)t & 0xFFFFu;
            u64 e = 0;
            if (!dead) {
                int sp = 0;
                for (;;) {
                    e = __hip_atomic_load(src, __ATOMIC_RELAXED,
                                          __HIP_MEMORY_SCOPE_AGENT);
                    if ((((unsigned)(e >> 16) & 0xFFFFu) == tg) &
                        ((unsigned)(e >> 48) == tg)) break;
                    if (++sp > (1 << 21)) { dead = true; break; }
                    __builtin_amdgcn_s_sleep(1);
                }
            }
            const int k0 = tid * 2;
            float2 hv;
            hv.x = h16f((unsigned short)(e & 0xFFFFu));
            hv.y = h16f((unsigned short)((e >> 32) & 0xFFFFu));
            *(float2*)&lds_h[b][(k0 >> 6) * PAD + (k0 & 63)] = hv;
            __syncthreads();

            const float* lh = &lds_h[b][kc * PAD];
            float4 h0 = *(const float4*)(lh + 0),  h1 = *(const float4*)(lh + 4);
            float4 h2 = *(const float4*)(lh + 8),  h3 = *(const float4*)(lh + 12);
            float4 h4 = *(const float4*)(lh + 16), h5 = *(const float4*)(lh + 20);
            float4 h6 = *(const float4*)(lh + 24), h7 = *(const float4*)(lh + 28);
            s  = DOT4(w0,h0) + DOT4(w1,h1) + DOT4(w2,h2) + DOT4(w3,h3);
            s += DOT4(w4,h4) + DOT4(w5,h5) + DOT4(w6,h6) + DOT4(w7,h7);
            float4 h8 = *(const float4*)(lh + 32), h9 = *(const float4*)(lh + 36);
            float4 ha = *(const float4*)(lh + 40), hb = *(const float4*)(lh + 44);
            float4 hc = *(const float4*)(lh + 48), hd = *(const float4*)(lh + 52);
            float4 he = *(const float4*)(lh + 56), hf = *(const float4*)(lh + 60);
            s += DOT4(w8,h8) + DOT4(w9,h9) + DOT4(wa,ha) + DOT4(wb,hb);
            s += DOT4(wc,hc) + DOT4(wd,hd) + DOT4(we,he) + DOT4(wf,hf);
        }

        s += __shfl_xor(s, 1);
        s += __shfl_xor(s, 2);
        s += __shfl_xor(s, 4);
        s += __shfl_xor(s, 8);

        float pg = s + xgv;
        float act = a_mul * fast_sigmoid(a_scl * pg) + a_add;

        float sf = __shfl(act, 16);
        float tg2 = __shfl(act, 32);
        float so = __shfl(act, 48);

        if (l == 0) {
            float si = act;
            c_state = sf * c_state + si * tg2;
            float hval = so * fast_tanh(c_state);
            u32 pk = (((u32)(t + 1) & 0xFFFFu) << 16) | (u32)fh16(hval);
            __hip_atomic_store(hp + (size_t)(t & 1) * HID + unit, pk,
                               __ATOMIC_RELAXED, __HIP_MEMORY_SCOPE_AGENT);
        }
        asm volatile("s_waitcnt vmcnt(0)" ::: "memory");

        if (t + 1 < T_SEQ && kc == 0) {
            xgv = xgd[(size_t)(t + 1) * 4096 + grow];
            asm volatile("" : "+v"(xgv));
        }
    }
}

// ---------------- head
__global__ void head_kernel(const float* __restrict__ W_ho,
                            const float* __restrict__ b_ho,
                            const u32* __restrict__ hpack,
                            float* __restrict__ out)
{
    const u32* hf  = hpack + 1 * HID;            // dir0 buf1
    const u32* hbk = hpack + 3 * HID;            // dir1 buf1
    __shared__ float r0[4], r1[4], r2[4];
    int tid = threadIdx.x;  // 256
    float p0 = 0.f, p1 = 0.f, p2 = 0.f;
    for (int i = tid; i < 2 * HID; i += 256) {
        u32 e = (i < HID) ? hf[i] : hbk[i - HID];
        _Float16 hh; unsigned short us = (unsigned short)(e & 0xFFFFu);
        __builtin_memcpy(&hh, &us, 2);
        float hv = (float)hh;
        p0 += W_ho[0 * 2 * HID + i] * hv;
        p1 += W_ho[1 * 2 * HID + i] * hv;
        p2 += W_ho[2 * 2 * HID + i] * hv;
    }
    #pragma unroll
    for (int m = 1; m < 64; m <<= 1) {
        p0 += __shfl_xor(p0, m);
        p1 += __shfl_xor(p1, m);
        p2 += __shfl_xor(p2, m);
    }
    int w = tid >> 6;
    if ((tid & 63) == 0) { r0[w] = p0; r1[w] = p1; r2[w] = p2; }
    __syncthreads();
    if (tid == 0) {
        out[0] = b_ho[0] + r0[0] + r0[1] + r0[2] + r0[3];
        out[1] = b_ho[1] + r1[0] + r1[1] + r1[2] + r1[3];
        out[2] = b_ho[2] + r2[0] + r2[1] + r2[2] + r2[3];
    }
}

extern "C" void kernel_launch(void* const* d_in, const int* in_sizes, int n_in,
                              void* d_out, int out_size, void* d_ws, size_t ws_size,
                              hipStream_t stream) {
    const float* x     = (const float*)d_in[0];
    const float* Wih_f = (const float*)d_in[1];
    const float* Whh_f = (const float*)d_in[2];
    const float* bih_f = (const float*)d_in[3];
    const float* bhh_f = (const float*)d_in[4];
    const float* Wih_b = (const float*)d_in[5];
    const float* Whh_b = (const float*)d_in[6];
    const float* bih_b = (const float*)d_in[7];
    const float* bhh_b = (const float*)d_in[8];
    const float* W_ho  = (const float*)d_in[9];
    const float* b_ho  = (const float*)d_in[10];

    u32* hpack = (u32*)d_ws;                           // 16 KB packed (tag16|h16)
    float* xg = (float*)((char*)d_ws + 32768);         // 128 MiB xg
    const size_t xg_bytes = (size_t)2 * 4096 * 4096 * sizeof(float);
    char* f16base = (char*)d_ws + 32768 + xg_bytes;
    _Float16* x16  = (_Float16*)f16base;                          // 8 MiB
    _Float16* w16f = (_Float16*)(f16base + (size_t)8 * 1024 * 1024);
    _Float16* w16b = (_Float16*)(f16base + (size_t)16 * 1024 * 1024);
    const size_t need_mfma = 32768 + xg_bytes + (size_t)24 * 1024 * 1024;

    // zero tags every call (ws poisoned once, never re-poisoned between replays)
    hipMemsetAsync(d_ws, 0, 2 * 2 * HID * sizeof(u32), stream);

    const int NCONV = T_SEQ * ISZ;                     // 4.19M elems each
    if (ws_size >= need_mfma) {
        f32_to_f16<<<NCONV / 8 / 256, 256, 0, stream>>>(x, x16, NCONV);
        f32_to_f16<<<NCONV / 8 / 256, 256, 0, stream>>>(Wih_f, w16f, NCONV);
        f32_to_f16<<<NCONV / 8 / 256, 256, 0, stream>>>(Wih_b, w16b, NCONV);
        dim3 gg(4096 / 64, 4096 / 64, 2);
        xproj_mfma<<<gg, 256, 0, stream>>>(x16, w16f, w16b,
                                           bih_f, bhh_f, bih_b, bhh_b, xg);
    } else {
        dim3 gg(4096 / GN, T_SEQ / GM, 2);
        xproj_gemm<<<gg, 256, 0, stream>>>(x, Wih_f, bih_f, bhh_f,
                                           Wih_b, bih_b, bhh_b, xg);
    }
    bilstm_rec<<<NB_TOT, NTHR, 0, stream>>>(xg, Whh_f, Whh_b, hpack);
    head_kernel<<<1, 256, 0, stream>>>(W_ho, b_ho, hpack, (float*)d_out);
}